// Round 5
// baseline (182.496 us; speedup 1.0000x reference)
//
#include <hip/hip_runtime.h>
#include <stdint.h>

#define GLOBAL_AS __attribute__((address_space(1)))
#define LDS_AS __attribute__((address_space(3)))

typedef _Float16 half_t;
typedef _Float16 f16x8 __attribute__((ext_vector_type(8)));
typedef float f32x4 __attribute__((ext_vector_type(4)));

static constexpr int BATCH = 8;
static constexpr int CH = 256;
static constexpr int N = 2304;     // 48*48
static constexpr int KTOT = 4096;  // 2 * BATCH * CH (G1 and G2 fused along K)
static constexpr int MW = 72;      // mask words per row (2304/32)
static constexpr int MWORDS = 165888;  // 2304*72
static constexpr int LROW = 258;   // LDS transpose row stride in halfs (odd word count)
static constexpr float EPS = 1e-8f;
static constexpr float THR = 31.5f;
static constexpr int NBLK = 243;   // 81 output tiles x 3 K-slices (single round, 1 blk/CU)

// ws layout (nothing needs pre-zeroing; every slot written unconditionally):
//   s_part  = ws         : float [243]  per-gemm-block masked-sum partials
//   c_part  = ws + 8192  : uint  [864]  per-mask-block popcount partials
//   At = ws + 16384            : half [2304][4096] rows=n, k-contig ([yhat; zhat])
//   Bt = At + 18874368 B       : half [2304][4096] rows=m, k-contig ([zphat; yphat])
//   maskw = Bt + 18874368 B    : uint32 [2304][72] bitmask of (dist < THR)

// ------------- 1. prep: fused norm+pack (z<4) and mask build (z>=4) -------------
__global__ __launch_bounds__(256) void prep_kernel(
    const float* __restrict__ y, const float* __restrict__ yp,
    const float* __restrict__ z, const float* __restrict__ zp,
    const float* __restrict__ dist,
    half_t* __restrict__ At, half_t* __restrict__ Bt,
    uint32_t* __restrict__ maskw, unsigned int* __restrict__ c_part) {
  const int t = threadIdx.x;
  const int bz = blockIdx.z;

  if (bz >= 4) {
    // ---- mask path: 3*8*36 = 864 blocks cover 165888 words ----
    const int blk = ((bz - 4) * 8 + blockIdx.y) * 36 + blockIdx.x;
    const int w = blk * 256 + t;
    int c = 0;
    if (w < MWORDS) {
      const float4* p = (const float4*)(dist + (size_t)w * 32);
      uint32_t bits = 0;
#pragma unroll
      for (int q = 0; q < 8; ++q) {
        float4 v = p[q];
        bits |= (v.x < THR ? 1u : 0u) << (q * 4);
        bits |= (v.y < THR ? 1u : 0u) << (q * 4 + 1);
        bits |= (v.z < THR ? 1u : 0u) << (q * 4 + 2);
        bits |= (v.w < THR ? 1u : 0u) << (q * 4 + 3);
      }
      maskw[w] = bits;
      c = __popc(bits);
    }
#pragma unroll
    for (int off = 32; off; off >>= 1) c += __shfl_down(c, off, 64);
    __shared__ int mred[4];
    if ((t & 63) == 0) mred[t >> 6] = c;
    __syncthreads();
    if (t == 0)
      c_part[blk] = (unsigned int)(mred[0] + mred[1] + mred[2] + mred[3]);
    return;
  }

  // ---- pack path: block = (tensor, batch, 64-n tile). Thread t owns 4 n's
  // ((t&15)*4+j) and one 16-channel k-chunk (cb=t>>4); 16 strided float4 loads
  // land its data k-contiguously in registers. Norms via small LDS reduce;
  // fp16 results staged through an LDS transpose tile so global stores are
  // 256-B contiguous runs (16 lanes x 16 B, same row).
  const int b = blockIdx.y;
  const int n0 = blockIdx.x * 64;  // 36*64 = 2304
  const float* src; half_t* dst; int kh;
  switch (bz) {
    case 0:  src = y;  dst = At; kh = 0;    break;
    case 1:  src = z;  dst = At; kh = 2048; break;
    case 2:  src = zp; dst = Bt; kh = 0;    break;
    default: src = yp; dst = Bt; kh = 2048; break;
  }
  const int kbase = kh + b * 256;
  const int col4 = (t & 15) * 4;   // n offset within tile
  const int cb = t >> 4;           // 16-channel k-chunk

  const float* base = src + (size_t)(b * CH + cb * 16) * N + n0 + col4;
  float4 v[16];
#pragma unroll
  for (int i = 0; i < 16; ++i) v[i] = *(const float4*)(base + (size_t)i * N);

  float ss[4] = {0.f, 0.f, 0.f, 0.f};
#pragma unroll
  for (int i = 0; i < 16; ++i) {
    ss[0] = fmaf(v[i].x, v[i].x, ss[0]);
    ss[1] = fmaf(v[i].y, v[i].y, ss[1]);
    ss[2] = fmaf(v[i].z, v[i].z, ss[2]);
    ss[3] = fmaf(v[i].w, v[i].w, ss[3]);
  }
  __shared__ float partial[16][65];
  __shared__ float sc[64];
  __shared__ half_t tile[64 * LROW];  // transpose staging, odd word row stride
#pragma unroll
  for (int j = 0; j < 4; ++j) partial[cb][col4 + j] = ss[j];
  __syncthreads();
  if (t < 64) {
    float s = 0.f;
#pragma unroll
    for (int k = 0; k < 16; ++k) s += partial[k][t];
    sc[t] = 1.0f / fmaxf(sqrtf(s), EPS);
  }
  __syncthreads();

  // normalize -> fp16 -> LDS transpose tile
#pragma unroll
  for (int j = 0; j < 4; ++j) {
    const float scj = sc[col4 + j];
    union { half_t h[16]; f16x8 v2[2]; } u;
#pragma unroll
    for (int i = 0; i < 16; ++i)
      u.h[i] = (half_t)(((const float*)&v[i])[j] * scj);
    f16x8* q = (f16x8*)(tile + (col4 + j) * LROW + cb * 16);
    q[0] = u.v2[0];
    q[1] = u.v2[1];
  }
  __syncthreads();

  // write-out: thread (r = t>>4, c = t&15); 4 row-passes x 2 instr;
  // each instruction: 16 lanes x 16 B contiguous in one row (256-B runs).
  {
    const int r = t >> 4, c = t & 15;
#pragma unroll
    for (int p = 0; p < 4; ++p) {
      const int row = p * 16 + r;
      half_t* gout = dst + (size_t)(n0 + row) * KTOT + kbase;
      const half_t* lrow = tile + row * LROW;
#pragma unroll
      for (int inst = 0; inst < 2; ++inst) {
        const int off = c * 8 + inst * 128;
        *(f16x8*)(gout + off) = *(const f16x8*)(lrow + off);
      }
    }
  }
}

// ---------------- 2. GEMM s_part[bid] = sum_mask (At * Bt^T) tile ----------------
// R4 structure (m201 8-phase, 256x256 tile, 8 waves 128x64, BK=64, 2 LDS bufs,
// counted vmcnt at P4/P8) PLUS one-phase-lookahead fragment reads (R4 post-
// mortem: reads sat in the serial slot between barriers -> LDS engine and
// matrix pipe strictly time-sliced; 10550 cy/iter ~= reads 4626 + MFMA 4966
// + skew with ZERO overlap).  Now each phase is:
//   [stage gload_lds] [vmcnt gate @P4/P8] [s_barrier; lgkmcnt(0)]
//   [issue NEXT phase's 4-8 ds_read_b128] [16 MFMA] [s_barrier]
// so phase p+1's frags return under phase p's ~620-cy MFMA window, and the
// lgkmcnt(0) at p+1's top finds them already complete.  Frag regs double-
// buffered as named sets afX/afY, bfX/bfY (static indexing, rule 20).
// Hazards: every lookahead targets the opposite buffer from in-flight staging;
// cross-tile lookaheads (P4 -> buf1, P8 -> next buf0) issue only after that
// tile's vmcnt(2)+barrier gate (each wave gates its own symmetric slice pre-
// barrier -> full tile landed post-barrier).  vmcnt ledger (incl. prev-P8
// carryover): 10 outstanding at each gate, vmcnt(2) retires exactly the
// consumed tile.  K-split 22/22/20 BK=64 tiles; swizzle/epilogue unchanged.
__global__ __launch_bounds__(512, 2) void gemm_kernel(
    const half_t* __restrict__ At, const half_t* __restrict__ Bt,
    const uint32_t* __restrict__ maskw, float* __restrict__ s_part) {
  __shared__ __align__(16) half_t As[2 * 16384];  // 2 bufs x 256 rows x 64 halfs
  __shared__ __align__(16) half_t Bs[2 * 16384];
  __shared__ float red[8];

  const int t = threadIdx.x;
  const int lane = t & 63;
  const int w8 = t >> 6;

  // bijective XCD swizzle (m204; 243 = 8*30 + 3): same-panel blocks same XCD
  const int orig = blockIdx.x;
  const int xcd = orig & 7;
  const int wid = (xcd < 3 ? xcd * 31 : 93 + (xcd - 3) * 30) + (orig >> 3);
  const int zt = wid / 81;          // K-slice
  const int t81 = wid % 81;
  const int n0 = (t81 / 9) * 256;   // At (n) tile base
  const int m0 = (t81 % 9) * 256;   // Bt (m) tile base
  const int k0 = zt * 1408;         // 22/22/20 BK=64 tiles
  const int NI = (zt == 2) ? 10 : 11;  // iterations (2 tiles each)

  // staging: one global_load_lds = 512 threads x 16 B = 64 rows x 64 halfs.
  // thread -> row t>>3, phys chunk t&7; fetch global chunk (t&7)^(row&7).
  const int srow = t >> 3;
  const int schunk8 = ((t & 7) ^ (srow & 7)) * 8;  // halfs
  const half_t* gA = At + (size_t)(n0 + srow) * KTOT + k0 + schunk8;
  const half_t* gB = Bt + (size_t)(m0 + srow) * KTOT + k0 + schunk8;
  const int ldsw = w8 * 512;  // wave-uniform LDS base offset (halfs)

  auto SA = [&](int tl, int u, int buf) {  // stage A unit u (64 rows) of K-tile tl
    __builtin_amdgcn_global_load_lds(
        (const GLOBAL_AS void*)(gA + (size_t)(u * 64) * KTOT + tl * 64),
        (LDS_AS void*)(As + buf * 16384 + u * 4096 + ldsw), 16, 0, 0);
  };
  auto SB = [&](int tl, int u, int buf) {
    __builtin_amdgcn_global_load_lds(
        (const GLOBAL_AS void*)(gB + (size_t)(u * 64) * KTOT + tl * 64),
        (LDS_AS void*)(Bs + buf * 16384 + u * 4096 + ldsw), 16, 0, 0);
  };

  // fragment addressing: wave (wA,wB) owns n in [wA*128,+128), m in [wB*64,+64).
  const int fr = lane & 15;   // row-within-frag
  const int cl = lane >> 4;   // logical k-chunk within k-half
  const int e = lane & 7;     // = fr & 7 (row parity for swizzle)
  const int ksw0 = ((((cl ^ e) & 3)) | (e & 4)) * 8;  // phys chunk, k-half 0
  const int ksw1 = ksw0 ^ 32;                         // k-half 1 flips bit2
  const int wA = w8 >> 2;
  const int wB = w8 & 3;
  const int aoff = (wA * 128 + fr) * 64;  // + qa*4096 + pos*1024 + ksw
  const int boff = (wB * 64 + fr) * 64;   // + pos*1024 + ksw

  f32x4 acc[8][4] = {};
  f16x8 afX[4], afY[4], bfX[4], bfY[4];

#define RD_A(DST, BUF, QA, KSW)                                                \
  _Pragma("unroll") for (int i = 0; i < 4; ++i)                                \
      DST[i] = *(const f16x8*)(As + (BUF) * 16384 + aoff + (QA) * 4096 +       \
                               i * 1024 + (KSW));
#define RD_B(DST, BUF, KSW)                                                    \
  _Pragma("unroll") for (int j_ = 0; j_ < 4; ++j_)                             \
      DST[j_] = *(const f16x8*)(Bs + (BUF) * 16384 + boff + j_ * 1024 + (KSW));
#define MM(QA, AF, BF)                                                         \
  __builtin_amdgcn_s_setprio(1);                                               \
  _Pragma("unroll") for (int i_ = 0; i_ < 4; ++i_)                             \
    _Pragma("unroll") for (int j_ = 0; j_ < 4; ++j_)                           \
      acc[(QA) * 4 + i_][j_] = __builtin_amdgcn_mfma_f32_16x16x32_f16(         \
          AF[i_], BF[j_], acc[(QA) * 4 + i_][j_], 0, 0, 0);                    \
  __builtin_amdgcn_s_setprio(0);
#define BARMID                                                                 \
  __builtin_amdgcn_s_barrier();                                                \
  asm volatile("s_waitcnt lgkmcnt(0)" ::: "memory");
#define BAREND __builtin_amdgcn_s_barrier();

// one iteration: tiles 2j (buf0) and u=2j+1 (buf1); stage u's remaining units
// (P1-P3), t2=2j+2 (P4-P7), t3=2j+3's A0,A2 (P8) when SN.  Frag reads for
// phase p+1 issue inside phase p's MFMA region (post-BARMID).
#define ITER(SN)                                                               \
  {                                                                            \
    const int u = 2 * j + 1, t2 = 2 * j + 2, t3 = 2 * j + 3;                   \
    /* P1: MM qa0 (buf0,k0); look ahead afY <- (buf0,qa1,k0) */                \
    SA(u, 1, 1); SA(u, 3, 1);                                                  \
    BARMID;                                                                    \
    RD_A(afY, 0, 1, ksw0);                                                     \
    MM(0, afX, bfX); BAREND;                                                   \
    /* P2: MM qa1 (buf0,k0); look ahead afX,bfY <- (buf0,k1) */                \
    SB(u, 0, 1); SB(u, 1, 1);                                                  \
    BARMID;                                                                    \
    RD_A(afX, 0, 0, ksw1); RD_B(bfY, 0, ksw1);                                 \
    MM(1, afY, bfX); BAREND;                                                   \
    /* P3: MM qa0 (buf0,k1); look ahead afY <- (buf0,qa1,k1) */                \
    SB(u, 2, 1); SB(u, 3, 1);                                                  \
    BARMID;                                                                    \
    RD_A(afY, 0, 1, ksw1);                                                     \
    MM(0, afX, bfY); BAREND;                                                   \
    /* P4: MM qa1 (buf0,k1); gate tile u; look ahead afX,bfX <- (buf1,k0) */   \
    if (SN) {                                                                  \
      SA(t2, 0, 0); SA(t2, 2, 0);                                              \
      asm volatile("s_waitcnt vmcnt(2)" ::: "memory");                         \
    } else {                                                                   \
      asm volatile("s_waitcnt vmcnt(0)" ::: "memory");                         \
    }                                                                          \
    BARMID;                                                                    \
    RD_A(afX, 1, 0, ksw0); RD_B(bfX, 1, ksw0);                                 \
    MM(1, afY, bfY); BAREND;                                                   \
    /* P5: MM qa0 (buf1,k0); look ahead afY <- (buf1,qa1,k0) */                \
    if (SN) { SA(t2, 1, 0); SA(t2, 3, 0); }                                    \
    BARMID;                                                                    \
    RD_A(afY, 1, 1, ksw0);                                                     \
    MM(0, afX, bfX); BAREND;                                                   \
    /* P6: MM qa1 (buf1,k0); look ahead afX,bfY <- (buf1,k1) */                \
    if (SN) { SB(t2, 0, 0); SB(t2, 1, 0); }                                    \
    BARMID;                                                                    \
    RD_A(afX, 1, 0, ksw1); RD_B(bfY, 1, ksw1);                                 \
    MM(1, afY, bfX); BAREND;                                                   \
    /* P7: MM qa0 (buf1,k1); look ahead afY <- (buf1,qa1,k1) */                \
    if (SN) { SB(t2, 2, 0); SB(t2, 3, 0); }                                    \
    BARMID;                                                                    \
    RD_A(afY, 1, 1, ksw1);                                                     \
    MM(0, afX, bfY); BAREND;                                                   \
    /* P8: MM qa1 (buf1,k1); gate t2; look ahead next-iter (buf0,k0) */        \
    if (SN) {                                                                  \
      SA(t3, 0, 1); SA(t3, 2, 1);                                              \
      asm volatile("s_waitcnt vmcnt(2)" ::: "memory");                         \
    }                                                                          \
    BARMID;                                                                    \
    if (SN) { RD_A(afX, 0, 0, ksw0); RD_B(bfX, 0, ksw0); }                     \
    MM(1, afY, bfY); BAREND;                                                   \
  }

  // prologue: tile0 fully (8 loads) + tile1 units A0,A2 (2 loads); gate tile0;
  // then preload P1's frags (buf0, qa0, k0).
  SA(0, 0, 0); SA(0, 1, 0); SA(0, 2, 0); SA(0, 3, 0);
  SB(0, 0, 0); SB(0, 1, 0); SB(0, 2, 0); SB(0, 3, 0);
  SA(1, 0, 1); SA(1, 2, 1);
  asm volatile("s_waitcnt vmcnt(2)" ::: "memory");
  __builtin_amdgcn_s_barrier();
  RD_A(afX, 0, 0, ksw0);
  RD_B(bfX, 0, ksw0);

  int j = 0;
  for (; j < NI - 1; ++j) ITER(true);
  ITER(false);
#undef ITER
#undef RD_A
#undef RD_B
#undef MM
#undef BARMID
#undef BAREND

  // masked-sum epilogue; C/D: col = lane&15 (m, 2nd operand), row = cl*4+reg (n).
  // acc[a][j]: n rows n0 + wA*128 + a*16, m cols m0 + wB*64 + j*16.
  float local = 0.f;
  const int mw0 = (m0 + wB * 64) >> 5;  // even -> uint2-aligned
#pragma unroll
  for (int i = 0; i < 8; ++i) {
    const int ng = n0 + wA * 128 + i * 16 + cl * 4;
#pragma unroll
    for (int r = 0; r < 4; ++r) {
      const uint2 wv = *(const uint2*)(maskw + (size_t)(ng + r) * MW + mw0);
#pragma unroll
      for (int j2 = 0; j2 < 4; ++j2) {
        const uint32_t ww = (j2 & 2) ? wv.y : wv.x;
        if ((ww >> (fr + ((j2 & 1) << 4))) & 1u) local += acc[i][j2][r];
      }
    }
  }
#pragma unroll
  for (int off = 32; off; off >>= 1) local += __shfl_down(local, off, 64);
  if (lane == 0) red[w8] = local;
  __syncthreads();
  if (t == 0) {
    float s = 0.f;
#pragma unroll
    for (int k = 0; k < 8; ++k) s += red[k];
    s_part[orig] = s;
  }
}

// ------- 3. finalize: reduce 243 s-partials + 864 count-partials -------
__global__ void finalize_kernel(const float* __restrict__ s_part,
                                const unsigned int* __restrict__ c_part,
                                float* __restrict__ out) {
  const int t = threadIdx.x;
  float local = 0.f;
  for (int i = t; i < NBLK; i += 256) local += s_part[i];
  unsigned int clocal = 0;
  for (int i = t; i < 864; i += 256) clocal += c_part[i];
#pragma unroll
  for (int off = 32; off; off >>= 1) {
    local += __shfl_down(local, off, 64);
    clocal += __shfl_down(clocal, off, 64);
  }
  __shared__ float red[4];
  __shared__ unsigned int credu[4];
  if ((t & 63) == 0) { red[t >> 6] = local; credu[t >> 6] = clocal; }
  __syncthreads();
  if (t == 0) {
    const float s = red[0] + red[1] + red[2] + red[3];
    const float cnt = (float)(credu[0] + credu[1] + credu[2] + credu[3]);
    out[0] = -s / (cnt * (float)BATCH);
  }
}

extern "C" void kernel_launch(void* const* d_in, const int* in_sizes, int n_in,
                              void* d_out, int out_size, void* d_ws, size_t ws_size,
                              hipStream_t stream) {
  const float* y    = (const float*)d_in[0];
  const float* yp   = (const float*)d_in[1];
  const float* z    = (const float*)d_in[2];
  const float* zp   = (const float*)d_in[3];
  const float* dist = (const float*)d_in[4];
  float* out = (float*)d_out;

  char* ws = (char*)d_ws;
  float* s_part = (float*)ws;
  unsigned int* c_part = (unsigned int*)(ws + 8192);
  half_t* At = (half_t*)(ws + 16384);
  half_t* Bt = (half_t*)(ws + 16384 + 18874368);
  uint32_t* maskw = (uint32_t*)(ws + 16384 + 2 * 18874368);

  prep_kernel<<<dim3(36, 8, 7), 256, 0, stream>>>(y, yp, z, zp, dist, At, Bt, maskw, c_part);
  gemm_kernel<<<dim3(NBLK), 512, 0, stream>>>(At, Bt, maskw, s_part);
  finalize_kernel<<<1, 256, 0, stream>>>(s_part, c_part, out);
}

// Round 6
// 176.889 us; speedup vs baseline: 1.0317x; 1.0317x over previous
//
#include <hip/hip_runtime.h>
#include <stdint.h>

#define GLOBAL_AS __attribute__((address_space(1)))
#define LDS_AS __attribute__((address_space(3)))

typedef _Float16 half_t;
typedef _Float16 f16x8 __attribute__((ext_vector_type(8)));
typedef float f32x4 __attribute__((ext_vector_type(4)));

static constexpr int BATCH = 8;
static constexpr int CH = 256;
static constexpr int N = 2304;     // 48*48
static constexpr int KTOT = 4096;  // 2 * BATCH * CH (G1 and G2 fused along K)
static constexpr int MW = 72;      // mask words per row (2304/32)
static constexpr int MWORDS = 165888;  // 2304*72
static constexpr int LROW = 258;   // LDS transpose row stride in halfs (odd word count)
static constexpr float EPS = 1e-8f;
static constexpr float THR = 31.5f;
static constexpr int NBLK = 972;   // 18x18 output tiles x 3 K-slices, 2 blocks/CU

// ws layout (nothing needs pre-zeroing; every slot written unconditionally):
//   s_part  = ws         : float [972]  per-gemm-block masked-sum partials
//   c_part  = ws + 8192  : uint  [864]  per-mask-block popcount partials
//   At = ws + 16384            : half [2304][4096] rows=n, k-contig ([yhat; zhat])
//   Bt = At + 18874368 B       : half [2304][4096] rows=m, k-contig ([zphat; yphat])
//   maskw = Bt + 18874368 B    : uint32 [2304][72] bitmask of (dist < THR)

// ------------- 1. prep: fused norm+pack (z<4) and mask build (z>=4) -------------
__global__ __launch_bounds__(256) void prep_kernel(
    const float* __restrict__ y, const float* __restrict__ yp,
    const float* __restrict__ z, const float* __restrict__ zp,
    const float* __restrict__ dist,
    half_t* __restrict__ At, half_t* __restrict__ Bt,
    uint32_t* __restrict__ maskw, unsigned int* __restrict__ c_part) {
  const int t = threadIdx.x;
  const int bz = blockIdx.z;

  if (bz >= 4) {
    // ---- mask path: 3*8*36 = 864 blocks cover 165888 words ----
    const int blk = ((bz - 4) * 8 + blockIdx.y) * 36 + blockIdx.x;
    const int w = blk * 256 + t;
    int c = 0;
    if (w < MWORDS) {
      const float4* p = (const float4*)(dist + (size_t)w * 32);
      uint32_t bits = 0;
#pragma unroll
      for (int q = 0; q < 8; ++q) {
        float4 v = p[q];
        bits |= (v.x < THR ? 1u : 0u) << (q * 4);
        bits |= (v.y < THR ? 1u : 0u) << (q * 4 + 1);
        bits |= (v.z < THR ? 1u : 0u) << (q * 4 + 2);
        bits |= (v.w < THR ? 1u : 0u) << (q * 4 + 3);
      }
      maskw[w] = bits;
      c = __popc(bits);
    }
#pragma unroll
    for (int off = 32; off; off >>= 1) c += __shfl_down(c, off, 64);
    __shared__ int mred[4];
    if ((t & 63) == 0) mred[t >> 6] = c;
    __syncthreads();
    if (t == 0)
      c_part[blk] = (unsigned int)(mred[0] + mred[1] + mred[2] + mred[3]);
    return;
  }

  // ---- pack path: block = (tensor, batch, 64-n tile). Thread t owns 4 n's
  // ((t&15)*4+j) and one 16-channel k-chunk (cb=t>>4); 16 strided float4 loads
  // land its data k-contiguously in registers. Norms via small LDS reduce;
  // fp16 results staged through an LDS transpose tile so global stores are
  // 256-B contiguous runs (16 lanes x 16 B, same row).
  const int b = blockIdx.y;
  const int n0 = blockIdx.x * 64;  // 36*64 = 2304
  const float* src; half_t* dst; int kh;
  switch (bz) {
    case 0:  src = y;  dst = At; kh = 0;    break;
    case 1:  src = z;  dst = At; kh = 2048; break;
    case 2:  src = zp; dst = Bt; kh = 0;    break;
    default: src = yp; dst = Bt; kh = 2048; break;
  }
  const int kbase = kh + b * 256;
  const int col4 = (t & 15) * 4;   // n offset within tile
  const int cb = t >> 4;           // 16-channel k-chunk

  const float* base = src + (size_t)(b * CH + cb * 16) * N + n0 + col4;
  float4 v[16];
#pragma unroll
  for (int i = 0; i < 16; ++i) v[i] = *(const float4*)(base + (size_t)i * N);

  float ss[4] = {0.f, 0.f, 0.f, 0.f};
#pragma unroll
  for (int i = 0; i < 16; ++i) {
    ss[0] = fmaf(v[i].x, v[i].x, ss[0]);
    ss[1] = fmaf(v[i].y, v[i].y, ss[1]);
    ss[2] = fmaf(v[i].z, v[i].z, ss[2]);
    ss[3] = fmaf(v[i].w, v[i].w, ss[3]);
  }
  __shared__ float partial[16][65];
  __shared__ float sc[64];
  __shared__ half_t tile[64 * LROW];  // transpose staging, odd word row stride
#pragma unroll
  for (int j = 0; j < 4; ++j) partial[cb][col4 + j] = ss[j];
  __syncthreads();
  if (t < 64) {
    float s = 0.f;
#pragma unroll
    for (int k = 0; k < 16; ++k) s += partial[k][t];
    sc[t] = 1.0f / fmaxf(sqrtf(s), EPS);
  }
  __syncthreads();

  // normalize -> fp16 -> LDS transpose tile
#pragma unroll
  for (int j = 0; j < 4; ++j) {
    const float scj = sc[col4 + j];
    union { half_t h[16]; f16x8 v2[2]; } u;
#pragma unroll
    for (int i = 0; i < 16; ++i)
      u.h[i] = (half_t)(((const float*)&v[i])[j] * scj);
    f16x8* q = (f16x8*)(tile + (col4 + j) * LROW + cb * 16);
    q[0] = u.v2[0];
    q[1] = u.v2[1];
  }
  __syncthreads();

  // write-out: thread (r = t>>4, c = t&15); 4 row-passes x 2 instr;
  // each instruction: 16 lanes x 16 B contiguous in one row (256-B runs).
  {
    const int r = t >> 4, c = t & 15;
#pragma unroll
    for (int p = 0; p < 4; ++p) {
      const int row = p * 16 + r;
      half_t* gout = dst + (size_t)(n0 + row) * KTOT + kbase;
      const half_t* lrow = tile + row * LROW;
#pragma unroll
      for (int inst = 0; inst < 2; ++inst) {
        const int off = c * 8 + inst * 128;
        *(f16x8*)(gout + off) = *(const f16x8*)(lrow + off);
      }
    }
  }
}

// ---------------- 2. GEMM s_part[bid] = sum_mask (At * Bt^T) tile ----------------
// R6: restore CROSS-BLOCK overlap (the only mechanism that measured well: R0's
// crude 2-block loop = 36% util; all single-block lockstep schedules R1/R4/R5
// = 27-35%).  256-thread blocks (4 waves, 2x2), 128x128 tile, BK=64, 2 LDS
// buffers = 64 KB -> TWO independent blocks per CU at mutually skewed phases:
// one block's ds_read/gate windows hide under the other's MFMA window (m114).
// Per-block schedule keeps R4's proven phase shape, 2 phases per K-tile:
//   P1: read frags(kh0) 8x b128 ; stage ALL 8 gload_lds of tile j+1 (buf^1) ;
//       barrier ; lgkmcnt(0) ; 16 MFMA ; barrier
//   P2: read frags(kh1) ; s_waitcnt vmcnt(0)  <- waits only loads aged >=1
//       phase (~600cy, mostly retired; never waits young loads) ; barrier ;
//       lgkmcnt(0) ; 16 MFMA ; barrier
// Gate audit: tile j+1's 8 loads all issue in P1(j); the vmcnt(0)+barrier at
// P2(j) precedes any read of buf^1 at P1(j+1) -> race-free.
// Grid: 18x18 tiles x K-split 3 (22/21/21 K-tiles) = 972 blocks = 1.9 rounds
// of the 512 block slots (~95% tail efficiency); bijective XCD swizzle
// (972 = 8*121+4).  LDS swizzle identical to R4 (phys chunk = logical ^
// (row&7), linear gload_lds dest + pre-swizzled source + swizzled ds_read;
// 2-way max bank aliasing = free).
__global__ __launch_bounds__(256, 2) void gemm_kernel(
    const half_t* __restrict__ At, const half_t* __restrict__ Bt,
    const uint32_t* __restrict__ maskw, float* __restrict__ s_part) {
  __shared__ __align__(16) half_t As[2 * 8192];  // 2 bufs x 128 rows x 64 halfs
  __shared__ __align__(16) half_t Bs[2 * 8192];
  __shared__ float red[4];

  const int t = threadIdx.x;
  const int lane = t & 63;
  const int w4 = t >> 6;

  // bijective XCD swizzle (972 = 8*121 + 4): xcd<4 -> 122 blocks, else 121.
  const int orig = blockIdx.x;
  const int xcd = orig & 7;
  const int wid = (xcd < 4 ? xcd * 122 : 488 + (xcd - 4) * 121) + (orig >> 3);
  const int zt = wid / 324;          // K-slice
  const int t324 = wid % 324;
  const int n0 = (t324 / 18) * 128;  // At (n) tile base
  const int m0 = (t324 % 18) * 128;  // Bt (m) tile base
  const int k0 = zt ? (1408 + (zt - 1) * 1344) : 0;  // 22/21/21 BK=64 tiles
  const int NT = zt ? 21 : 22;

  // staging: one global_load_lds = 256 threads x 16 B = 32 rows x 64 halfs.
  // thread -> row t>>3 (0..31), phys chunk t&7; fetch global chunk
  // (t&7)^(row&7) so linear LDS writes land the XOR-swizzled layout.
  const int srow = t >> 3;
  const int schunk8 = ((t & 7) ^ (srow & 7)) * 8;  // halfs
  const half_t* gA = At + (size_t)(n0 + srow) * KTOT + k0 + schunk8;
  const half_t* gB = Bt + (size_t)(m0 + srow) * KTOT + k0 + schunk8;
  const int ldsw = w4 * 512;  // wave-uniform LDS base (8 rows x 64 halfs)

  auto SA = [&](int tl, int u, int buf) {  // stage A unit u (32 rows) of tile tl
    __builtin_amdgcn_global_load_lds(
        (const GLOBAL_AS void*)(gA + (size_t)(u * 32) * KTOT + tl * 64),
        (LDS_AS void*)(As + buf * 8192 + u * 2048 + ldsw), 16, 0, 0);
  };
  auto SB = [&](int tl, int u, int buf) {
    __builtin_amdgcn_global_load_lds(
        (const GLOBAL_AS void*)(gB + (size_t)(u * 32) * KTOT + tl * 64),
        (LDS_AS void*)(Bs + buf * 8192 + u * 2048 + ldsw), 16, 0, 0);
  };

  // fragment addressing: wave (wA,wB) owns n in [wA*64,+64), m in [wB*64,+64).
  const int fr = lane & 15;   // row-within-frag
  const int cl = lane >> 4;   // logical k-chunk within k-half
  const int e = lane & 7;     // row parity for swizzle (== fr&7)
  const int ksw0 = ((((cl ^ e) & 3)) | (e & 4)) * 8;  // phys chunk, k-half 0
  const int ksw1 = ksw0 ^ 32;                         // k-half 1 flips bit2
  const int wA = w4 >> 1;
  const int wB = w4 & 1;
  const int aoff = (wA * 64 + fr) * 64;  // + i*1024 + ksw
  const int boff = (wB * 64 + fr) * 64;  // + j*1024 + ksw

  f32x4 acc[4][4] = {};
  f16x8 af[4], bf[4];

#define RD_A(BUF, KSW)                                                         \
  _Pragma("unroll") for (int i = 0; i < 4; ++i)                                \
      af[i] = *(const f16x8*)(As + (BUF) * 8192 + aoff + i * 1024 + (KSW));
#define RD_B(BUF, KSW)                                                         \
  _Pragma("unroll") for (int j_ = 0; j_ < 4; ++j_)                             \
      bf[j_] = *(const f16x8*)(Bs + (BUF) * 8192 + boff + j_ * 1024 + (KSW));
#define MM                                                                     \
  __builtin_amdgcn_s_setprio(1);                                               \
  _Pragma("unroll") for (int i_ = 0; i_ < 4; ++i_)                             \
    _Pragma("unroll") for (int j_ = 0; j_ < 4; ++j_)                           \
      acc[i_][j_] = __builtin_amdgcn_mfma_f32_16x16x32_f16(                    \
          af[i_], bf[j_], acc[i_][j_], 0, 0, 0);                               \
  __builtin_amdgcn_s_setprio(0);
#define BARMID                                                                 \
  __builtin_amdgcn_s_barrier();                                                \
  asm volatile("s_waitcnt lgkmcnt(0)" ::: "memory");
#define BAREND __builtin_amdgcn_s_barrier();

  // prologue: stage tile 0 fully (8 loads), drain, barrier.
  SA(0, 0, 0); SA(0, 1, 0); SA(0, 2, 0); SA(0, 3, 0);
  SB(0, 0, 0); SB(0, 1, 0); SB(0, 2, 0); SB(0, 3, 0);
  asm volatile("s_waitcnt vmcnt(0)" ::: "memory");
  __builtin_amdgcn_s_barrier();

  for (int j = 0; j < NT; ++j) {
    const int buf = j & 1;
    const bool sn = (j + 1 < NT);
    // P1: frags kh0; stage all of tile j+1 into buf^1
    RD_A(buf, ksw0); RD_B(buf, ksw0);
    if (sn) {
      SA(j + 1, 0, buf ^ 1); SA(j + 1, 1, buf ^ 1);
      SA(j + 1, 2, buf ^ 1); SA(j + 1, 3, buf ^ 1);
      SB(j + 1, 0, buf ^ 1); SB(j + 1, 1, buf ^ 1);
      SB(j + 1, 2, buf ^ 1); SB(j + 1, 3, buf ^ 1);
    }
    BARMID; MM; BAREND;
    // P2: frags kh1; gate tile j+1's loads (aged ~1 phase)
    RD_A(buf, ksw1); RD_B(buf, ksw1);
    asm volatile("s_waitcnt vmcnt(0)" ::: "memory");
    BARMID; MM; BAREND;
  }
#undef RD_A
#undef RD_B
#undef MM
#undef BARMID
#undef BAREND

  // masked-sum epilogue; C/D: col = lane&15 (m, 2nd operand), row = cl*4+reg (n).
  // acc[i][j]: n rows n0 + wA*64 + i*16, m cols m0 + wB*64 + j*16.
  float local = 0.f;
  const int mw0 = (m0 + wB * 64) >> 5;  // even -> uint2-aligned
#pragma unroll
  for (int i = 0; i < 4; ++i) {
    const int ng = n0 + wA * 64 + i * 16 + cl * 4;
#pragma unroll
    for (int r = 0; r < 4; ++r) {
      const uint2 wv = *(const uint2*)(maskw + (size_t)(ng + r) * MW + mw0);
#pragma unroll
      for (int j2 = 0; j2 < 4; ++j2) {
        const uint32_t ww = (j2 & 2) ? wv.y : wv.x;
        if ((ww >> (fr + ((j2 & 1) << 4))) & 1u) local += acc[i][j2][r];
      }
    }
  }
#pragma unroll
  for (int off = 32; off; off >>= 1) local += __shfl_down(local, off, 64);
  if (lane == 0) red[w4] = local;
  __syncthreads();
  if (t == 0) s_part[orig] = red[0] + red[1] + red[2] + red[3];
}

// ------- 3. finalize: reduce 972 s-partials + 864 count-partials -------
__global__ void finalize_kernel(const float* __restrict__ s_part,
                                const unsigned int* __restrict__ c_part,
                                float* __restrict__ out) {
  const int t = threadIdx.x;
  float local = 0.f;
  for (int i = t; i < NBLK; i += 256) local += s_part[i];
  unsigned int clocal = 0;
  for (int i = t; i < 864; i += 256) clocal += c_part[i];
#pragma unroll
  for (int off = 32; off; off >>= 1) {
    local += __shfl_down(local, off, 64);
    clocal += __shfl_down(clocal, off, 64);
  }
  __shared__ float red[4];
  __shared__ unsigned int credu[4];
  if ((t & 63) == 0) { red[t >> 6] = local; credu[t >> 6] = clocal; }
  __syncthreads();
  if (t == 0) {
    const float s = red[0] + red[1] + red[2] + red[3];
    const float cnt = (float)(credu[0] + credu[1] + credu[2] + credu[3]);
    out[0] = -s / (cnt * (float)BATCH);
  }
}

extern "C" void kernel_launch(void* const* d_in, const int* in_sizes, int n_in,
                              void* d_out, int out_size, void* d_ws, size_t ws_size,
                              hipStream_t stream) {
  const float* y    = (const float*)d_in[0];
  const float* yp   = (const float*)d_in[1];
  const float* z    = (const float*)d_in[2];
  const float* zp   = (const float*)d_in[3];
  const float* dist = (const float*)d_in[4];
  float* out = (float*)d_out;

  char* ws = (char*)d_ws;
  float* s_part = (float*)ws;
  unsigned int* c_part = (unsigned int*)(ws + 8192);
  half_t* At = (half_t*)(ws + 16384);
  half_t* Bt = (half_t*)(ws + 16384 + 18874368);
  uint32_t* maskw = (uint32_t*)(ws + 16384 + 2 * 18874368);

  prep_kernel<<<dim3(36, 8, 7), 256, 0, stream>>>(y, yp, z, zp, dist, At, Bt, maskw, c_part);
  gemm_kernel<<<dim3(NBLK), 256, 0, stream>>>(At, Bt, maskw, s_part);
  finalize_kernel<<<1, 256, 0, stream>>>(s_part, c_part, out);
}

// Round 7
// 172.108 us; speedup vs baseline: 1.0604x; 1.0278x over previous
//
#include <hip/hip_runtime.h>
#include <stdint.h>

#define GLOBAL_AS __attribute__((address_space(1)))
#define LDS_AS __attribute__((address_space(3)))

typedef _Float16 half_t;
typedef _Float16 f16x8 __attribute__((ext_vector_type(8)));
typedef float f32x4 __attribute__((ext_vector_type(4)));

static constexpr int BATCH = 8;
static constexpr int CH = 256;
static constexpr int N = 2304;     // 48*48
static constexpr int KTOT = 4096;  // 2 * BATCH * CH (G1 and G2 fused along K)
static constexpr int MW = 72;      // mask words per row (2304/32)
static constexpr int MWORDS = 165888;  // 2304*72
static constexpr int LROW = 258;   // LDS transpose row stride in halfs (odd word count)
static constexpr float EPS = 1e-8f;
static constexpr float THR = 31.5f;
static constexpr int NBLK = 243;   // 81 output tiles x 3 K-slices (single round, 1 blk/CU)

// ws layout (nothing needs pre-zeroing; every slot written unconditionally):
//   s_part  = ws         : float [243]  per-gemm-block masked-sum partials
//   c_part  = ws + 8192  : uint  [864]  per-mask-block popcount partials
//   At = ws + 16384            : half [2304][4096] rows=n, k-contig ([yhat; zhat])
//   Bt = At + 18874368 B       : half [2304][4096] rows=m, k-contig ([zphat; yphat])
//   maskw = Bt + 18874368 B    : uint32 [2304][72] bitmask of (dist < THR)

// ------------- 1. prep: fused norm+pack (z<4) and mask build (z>=4) -------------
__global__ __launch_bounds__(256) void prep_kernel(
    const float* __restrict__ y, const float* __restrict__ yp,
    const float* __restrict__ z, const float* __restrict__ zp,
    const float* __restrict__ dist,
    half_t* __restrict__ At, half_t* __restrict__ Bt,
    uint32_t* __restrict__ maskw, unsigned int* __restrict__ c_part) {
  const int t = threadIdx.x;
  const int bz = blockIdx.z;

  if (bz >= 4) {
    // ---- mask path: 3*8*36 = 864 blocks cover 165888 words ----
    const int blk = ((bz - 4) * 8 + blockIdx.y) * 36 + blockIdx.x;
    const int w = blk * 256 + t;
    int c = 0;
    if (w < MWORDS) {
      const float4* p = (const float4*)(dist + (size_t)w * 32);
      uint32_t bits = 0;
#pragma unroll
      for (int q = 0; q < 8; ++q) {
        float4 v = p[q];
        bits |= (v.x < THR ? 1u : 0u) << (q * 4);
        bits |= (v.y < THR ? 1u : 0u) << (q * 4 + 1);
        bits |= (v.z < THR ? 1u : 0u) << (q * 4 + 2);
        bits |= (v.w < THR ? 1u : 0u) << (q * 4 + 3);
      }
      maskw[w] = bits;
      c = __popc(bits);
    }
#pragma unroll
    for (int off = 32; off; off >>= 1) c += __shfl_down(c, off, 64);
    __shared__ int mred[4];
    if ((t & 63) == 0) mred[t >> 6] = c;
    __syncthreads();
    if (t == 0)
      c_part[blk] = (unsigned int)(mred[0] + mred[1] + mred[2] + mred[3]);
    return;
  }

  // ---- pack path: block = (tensor, batch, 64-n tile). Thread t owns 4 n's
  // ((t&15)*4+j) and one 16-channel k-chunk (cb=t>>4); 16 strided float4 loads
  // land its data k-contiguously in registers. Norms via small LDS reduce;
  // fp16 results staged through an LDS transpose tile so global stores are
  // 256-B contiguous runs (16 lanes x 16 B, same row).
  const int b = blockIdx.y;
  const int n0 = blockIdx.x * 64;  // 36*64 = 2304
  const float* src; half_t* dst; int kh;
  switch (bz) {
    case 0:  src = y;  dst = At; kh = 0;    break;
    case 1:  src = z;  dst = At; kh = 2048; break;
    case 2:  src = zp; dst = Bt; kh = 0;    break;
    default: src = yp; dst = Bt; kh = 2048; break;
  }
  const int kbase = kh + b * 256;
  const int col4 = (t & 15) * 4;   // n offset within tile
  const int cb = t >> 4;           // 16-channel k-chunk

  const float* base = src + (size_t)(b * CH + cb * 16) * N + n0 + col4;
  float4 v[16];
#pragma unroll
  for (int i = 0; i < 16; ++i) v[i] = *(const float4*)(base + (size_t)i * N);

  float ss[4] = {0.f, 0.f, 0.f, 0.f};
#pragma unroll
  for (int i = 0; i < 16; ++i) {
    ss[0] = fmaf(v[i].x, v[i].x, ss[0]);
    ss[1] = fmaf(v[i].y, v[i].y, ss[1]);
    ss[2] = fmaf(v[i].z, v[i].z, ss[2]);
    ss[3] = fmaf(v[i].w, v[i].w, ss[3]);
  }
  __shared__ float partial[16][65];
  __shared__ float sc[64];
  __shared__ half_t tile[64 * LROW];  // transpose staging, odd word row stride
#pragma unroll
  for (int j = 0; j < 4; ++j) partial[cb][col4 + j] = ss[j];
  __syncthreads();
  if (t < 64) {
    float s = 0.f;
#pragma unroll
    for (int k = 0; k < 16; ++k) s += partial[k][t];
    sc[t] = 1.0f / fmaxf(sqrtf(s), EPS);
  }
  __syncthreads();

  // normalize -> fp16 -> LDS transpose tile
#pragma unroll
  for (int j = 0; j < 4; ++j) {
    const float scj = sc[col4 + j];
    union { half_t h[16]; f16x8 v2[2]; } u;
#pragma unroll
    for (int i = 0; i < 16; ++i)
      u.h[i] = (half_t)(((const float*)&v[i])[j] * scj);
    f16x8* q = (f16x8*)(tile + (col4 + j) * LROW + cb * 16);
    q[0] = u.v2[0];
    q[1] = u.v2[1];
  }
  __syncthreads();

  // write-out: thread (r = t>>4, c = t&15); 4 row-passes x 2 instr;
  // each instruction: 16 lanes x 16 B contiguous in one row (256-B runs).
  {
    const int r = t >> 4, c = t & 15;
#pragma unroll
    for (int p = 0; p < 4; ++p) {
      const int row = p * 16 + r;
      half_t* gout = dst + (size_t)(n0 + row) * KTOT + kbase;
      const half_t* lrow = tile + row * LROW;
#pragma unroll
      for (int inst = 0; inst < 2; ++inst) {
        const int off = c * 8 + inst * 128;
        *(f16x8*)(gout + off) = *(const f16x8*)(lrow + off);
      }
    }
  }
}

// ---------------- 2. GEMM s_part[bid] = sum_mask (At * Bt^T) tile ----------------
// R7 = R4 (best kernel: m201 8-phase, 256x256 tile, 8 waves 128x64, BK=64,
// 2 LDS bufs, counted vmcnt at P4/P8) with ONE change: the explicit
// "s_waitcnt lgkmcnt(0)" drain after each phase barrier is REMOVED.
// R6 post-mortem: frag reads are plain C++ loads, so the compiler already
// inserts fine-grained COUNTED lgkmcnt before each MFMA (first MFMA starts
// after only af0/bf0 land, read tail overlaps the MFMA ramp); the manual
// drain + memory clobber forced all 8 reads to complete before MFMA #1 in
// EVERY phase — a lgkm-side drain-0, the exact stall T4 removes on the vmem
// side.  Cross-wave correctness unchanged: staging visibility = per-wave
// vmcnt gate (each wave gates its own slice pre-barrier) + s_barrier.
// Phase: [ds_read frags] [stage gload_lds] [vmcnt gate @P4/P8] [s_barrier]
//        [16 MFMA, compiler-counted lgkm waits] [s_barrier].
// K-split 22/22/20 BK=64 tiles; swizzle/staging/epilogue identical to R4.
__global__ __launch_bounds__(512, 2) void gemm_kernel(
    const half_t* __restrict__ At, const half_t* __restrict__ Bt,
    const uint32_t* __restrict__ maskw, float* __restrict__ s_part) {
  __shared__ __align__(16) half_t As[2 * 16384];  // 2 bufs x 256 rows x 64 halfs
  __shared__ __align__(16) half_t Bs[2 * 16384];
  __shared__ float red[8];

  const int t = threadIdx.x;
  const int lane = t & 63;
  const int w8 = t >> 6;

  // bijective XCD swizzle (m204; 243 = 8*30 + 3): same-panel blocks same XCD
  const int orig = blockIdx.x;
  const int xcd = orig & 7;
  const int wid = (xcd < 3 ? xcd * 31 : 93 + (xcd - 3) * 30) + (orig >> 3);
  const int zt = wid / 81;          // K-slice
  const int t81 = wid % 81;
  const int n0 = (t81 / 9) * 256;   // At (n) tile base
  const int m0 = (t81 % 9) * 256;   // Bt (m) tile base
  const int k0 = zt * 1408;         // 22/22/20 BK=64 tiles
  const int NI = (zt == 2) ? 10 : 11;  // iterations (2 tiles each)

  // staging: one global_load_lds = 512 threads x 16 B = 64 rows x 64 halfs.
  // thread -> row t>>3, phys chunk t&7; fetch global chunk (t&7)^(row&7).
  const int srow = t >> 3;
  const int schunk8 = ((t & 7) ^ (srow & 7)) * 8;  // halfs
  const half_t* gA = At + (size_t)(n0 + srow) * KTOT + k0 + schunk8;
  const half_t* gB = Bt + (size_t)(m0 + srow) * KTOT + k0 + schunk8;
  const int ldsw = w8 * 512;  // wave-uniform LDS base offset (halfs)

  auto SA = [&](int tl, int u, int buf) {  // stage A unit u (64 rows) of K-tile tl
    __builtin_amdgcn_global_load_lds(
        (const GLOBAL_AS void*)(gA + (size_t)(u * 64) * KTOT + tl * 64),
        (LDS_AS void*)(As + buf * 16384 + u * 4096 + ldsw), 16, 0, 0);
  };
  auto SB = [&](int tl, int u, int buf) {
    __builtin_amdgcn_global_load_lds(
        (const GLOBAL_AS void*)(gB + (size_t)(u * 64) * KTOT + tl * 64),
        (LDS_AS void*)(Bs + buf * 16384 + u * 4096 + ldsw), 16, 0, 0);
  };

  // fragment addressing: wave (wA,wB) owns n in [wA*128,+128), m in [wB*64,+64).
  const int fr = lane & 15;   // row-within-frag
  const int cl = lane >> 4;   // logical k-chunk within k-half
  const int e = lane & 7;     // = fr & 7 (row parity for swizzle)
  const int ksw0 = ((((cl ^ e) & 3)) | (e & 4)) * 8;  // phys chunk, k-half 0
  const int ksw1 = ksw0 ^ 32;                         // k-half 1 flips bit2
  const int wA = w8 >> 2;
  const int wB = w8 & 3;
  const int aoff = (wA * 128 + fr) * 64;  // + qa*4096 + pos*1024 + ksw
  const int boff = (wB * 64 + fr) * 64;   // + pos*1024 + ksw

  f32x4 acc[8][4] = {};
  f16x8 af[4], bf[4];

#define RD_A(BUF, QA, KSW)                                                     \
  _Pragma("unroll") for (int i = 0; i < 4; ++i)                                \
      af[i] = *(const f16x8*)(As + (BUF) * 16384 + aoff + (QA) * 4096 +        \
                              i * 1024 + (KSW));
#define RD_B(BUF, KSW)                                                         \
  _Pragma("unroll") for (int j_ = 0; j_ < 4; ++j_)                             \
      bf[j_] = *(const f16x8*)(Bs + (BUF) * 16384 + boff + j_ * 1024 + (KSW));
#define MM(QA)                                                                 \
  __builtin_amdgcn_s_setprio(1);                                               \
  _Pragma("unroll") for (int i_ = 0; i_ < 4; ++i_)                             \
    _Pragma("unroll") for (int j_ = 0; j_ < 4; ++j_)                           \
      acc[(QA) * 4 + i_][j_] = __builtin_amdgcn_mfma_f32_16x16x32_f16(         \
          af[i_], bf[j_], acc[(QA) * 4 + i_][j_], 0, 0, 0);                    \
  __builtin_amdgcn_s_setprio(0);
// phase barriers: raw s_barrier only — NO lgkm drain (compiler inserts
// counted lgkmcnt before each MFMA for its own ds_reads).
#define BARMID __builtin_amdgcn_s_barrier();
#define BAREND __builtin_amdgcn_s_barrier();

// one iteration: tiles 2j (buf0) and u=2j+1 (buf1); stage u's remaining
// units (P1-P3), then t2=2j+2 (P4-P7) and t3=2j+3's A0,A2 (P8) when SN.
#define ITER(SN)                                                               \
  {                                                                            \
    const int u = 2 * j + 1, t2 = 2 * j + 2, t3 = 2 * j + 3;                   \
    /* P1: (qa0,k0) */                                                         \
    RD_A(0, 0, ksw0); RD_B(0, ksw0);                                           \
    SA(u, 1, 1); SA(u, 3, 1);                                                  \
    BARMID; MM(0); BAREND;                                                     \
    /* P2: (qa1,k0) */                                                         \
    RD_A(0, 1, ksw0);                                                          \
    SB(u, 0, 1); SB(u, 1, 1);                                                  \
    BARMID; MM(1); BAREND;                                                     \
    /* P3: (qa0,k1) */                                                         \
    RD_A(0, 0, ksw1); RD_B(0, ksw1);                                           \
    SB(u, 2, 1); SB(u, 3, 1);                                                  \
    BARMID; MM(0); BAREND;                                                     \
    /* P4: (qa1,k1) + gate tile u */                                           \
    RD_A(0, 1, ksw1);                                                          \
    if (SN) {                                                                  \
      SA(t2, 0, 0); SA(t2, 2, 0);                                              \
      asm volatile("s_waitcnt vmcnt(2)" ::: "memory");                         \
    } else {                                                                   \
      asm volatile("s_waitcnt vmcnt(0)" ::: "memory");                         \
    }                                                                          \
    BARMID; MM(1); BAREND;                                                     \
    /* P5: (qa0,k0) of u */                                                    \
    RD_A(1, 0, ksw0); RD_B(1, ksw0);                                           \
    if (SN) { SA(t2, 1, 0); SA(t2, 3, 0); }                                    \
    BARMID; MM(0); BAREND;                                                     \
    /* P6 */                                                                   \
    RD_A(1, 1, ksw0);                                                          \
    if (SN) { SB(t2, 0, 0); SB(t2, 1, 0); }                                    \
    BARMID; MM(1); BAREND;                                                     \
    /* P7 */                                                                   \
    RD_A(1, 0, ksw1); RD_B(1, ksw1);                                           \
    if (SN) { SB(t2, 2, 0); SB(t2, 3, 0); }                                    \
    BARMID; MM(0); BAREND;                                                     \
    /* P8 + gate tile t2 */                                                    \
    RD_A(1, 1, ksw1);                                                          \
    if (SN) {                                                                  \
      SA(t3, 0, 1); SA(t3, 2, 1);                                              \
      asm volatile("s_waitcnt vmcnt(2)" ::: "memory");                         \
    }                                                                          \
    BARMID; MM(1); BAREND;                                                     \
  }

  // prologue: tile0 fully (8 loads) + tile1 units A0,A2 (2 loads); gate tile0.
  SA(0, 0, 0); SA(0, 1, 0); SA(0, 2, 0); SA(0, 3, 0);
  SB(0, 0, 0); SB(0, 1, 0); SB(0, 2, 0); SB(0, 3, 0);
  SA(1, 0, 1); SA(1, 2, 1);
  asm volatile("s_waitcnt vmcnt(2)" ::: "memory");
  __builtin_amdgcn_s_barrier();

  int j = 0;
  for (; j < NI - 1; ++j) ITER(true);
  ITER(false);
#undef ITER
#undef RD_A
#undef RD_B
#undef MM
#undef BARMID
#undef BAREND

  // masked-sum epilogue; C/D: col = lane&15 (m, 2nd operand), row = cl*4+reg (n).
  // acc[a][j]: n rows n0 + wA*128 + a*16, m cols m0 + wB*64 + j*16.
  float local = 0.f;
  const int mw0 = (m0 + wB * 64) >> 5;  // even -> uint2-aligned
#pragma unroll
  for (int i = 0; i < 8; ++i) {
    const int ng = n0 + wA * 128 + i * 16 + cl * 4;
#pragma unroll
    for (int r = 0; r < 4; ++r) {
      const uint2 wv = *(const uint2*)(maskw + (size_t)(ng + r) * MW + mw0);
#pragma unroll
      for (int j2 = 0; j2 < 4; ++j2) {
        const uint32_t ww = (j2 & 2) ? wv.y : wv.x;
        if ((ww >> (fr + ((j2 & 1) << 4))) & 1u) local += acc[i][j2][r];
      }
    }
  }
#pragma unroll
  for (int off = 32; off; off >>= 1) local += __shfl_down(local, off, 64);
  if (lane == 0) red[w8] = local;
  __syncthreads();
  if (t == 0) {
    float s = 0.f;
#pragma unroll
    for (int k = 0; k < 8; ++k) s += red[k];
    s_part[orig] = s;
  }
}

// ------- 3. finalize: reduce 243 s-partials + 864 count-partials -------
__global__ void finalize_kernel(const float* __restrict__ s_part,
                                const unsigned int* __restrict__ c_part,
                                float* __restrict__ out) {
  const int t = threadIdx.x;
  float local = 0.f;
  for (int i = t; i < NBLK; i += 256) local += s_part[i];
  unsigned int clocal = 0;
  for (int i = t; i < 864; i += 256) clocal += c_part[i];
#pragma unroll
  for (int off = 32; off; off >>= 1) {
    local += __shfl_down(local, off, 64);
    clocal += __shfl_down(clocal, off, 64);
  }
  __shared__ float red[4];
  __shared__ unsigned int credu[4];
  if ((t & 63) == 0) { red[t >> 6] = local; credu[t >> 6] = clocal; }
  __syncthreads();
  if (t == 0) {
    const float s = red[0] + red[1] + red[2] + red[3];
    const float cnt = (float)(credu[0] + credu[1] + credu[2] + credu[3]);
    out[0] = -s / (cnt * (float)BATCH);
  }
}

extern "C" void kernel_launch(void* const* d_in, const int* in_sizes, int n_in,
                              void* d_out, int out_size, void* d_ws, size_t ws_size,
                              hipStream_t stream) {
  const float* y    = (const float*)d_in[0];
  const float* yp   = (const float*)d_in[1];
  const float* z    = (const float*)d_in[2];
  const float* zp   = (const float*)d_in[3];
  const float* dist = (const float*)d_in[4];
  float* out = (float*)d_out;

  char* ws = (char*)d_ws;
  float* s_part = (float*)ws;
  unsigned int* c_part = (unsigned int*)(ws + 8192);
  half_t* At = (half_t*)(ws + 16384);
  half_t* Bt = (half_t*)(ws + 16384 + 18874368);
  uint32_t* maskw = (uint32_t*)(ws + 16384 + 2 * 18874368);

  prep_kernel<<<dim3(36, 8, 7), 256, 0, stream>>>(y, yp, z, zp, dist, At, Bt, maskw, c_part);
  gemm_kernel<<<dim3(NBLK), 512, 0, stream>>>(At, Bt, maskw, s_part);
  finalize_kernel<<<1, 256, 0, stream>>>(s_part, c_part, out);
}